// Round 1
// baseline (422.741 us; speedup 1.0000x reference)
//
#include <hip/hip_runtime.h>
#include <hip/hip_bf16.h>

#define SLOPE 0.2f
#define DH 256
#define DE 128

typedef __bf16 bf16_t;
typedef bf16_t bf16x8 __attribute__((ext_vector_type(8)));
typedef float f32x4 __attribute__((ext_vector_type(4)));

__device__ __forceinline__ float lrelu(float x) { return x > 0.f ? x : SLOPE * x; }

// ---------------------------------------------------------------------------
// Cast + transpose weights to bf16: wT[n][k] = wW[k][n]  (256x256)
//                                   ewT[n][k] = ewW[k][n] (256x128)
// ---------------------------------------------------------------------------
__global__ void prep_weights(const float* __restrict__ wW, const float* __restrict__ ewW,
                             bf16_t* __restrict__ wT, bf16_t* __restrict__ ewT) {
    int n = blockIdx.x;   // 0..255 (output col of original)
    int k = threadIdx.x;  // 0..255
    wT[n * 256 + k] = (bf16_t)wW[k * 256 + n];
    if (k < 128) ewT[n * 128 + k] = (bf16_t)ewW[k * 256 + n];
}

// ---------------------------------------------------------------------------
// Node projection: h = lrelu(nf @ wW + wb)  [N,256], bf16 out
// epilogue also computes s1 = h . aW[0:256], s2 = h . aW[256:512] (fp32)
// Tile: 64 rows/block, 256 threads (4 waves), wave w owns cols [w*64, w*64+64)
// ---------------------------------------------------------------------------
__global__ __launch_bounds__(256) void node_proj(const float* __restrict__ nf,
                                                 const bf16_t* __restrict__ wT,
                                                 const float* __restrict__ wb,
                                                 const float* __restrict__ aW,
                                                 bf16_t* __restrict__ h,
                                                 float* __restrict__ s1,
                                                 float* __restrict__ s2, int N) {
    __shared__ bf16_t A[64][264];  // 256 + 8 pad (stride 528B = 33*16B)
    __shared__ float p1[4][64];
    __shared__ float p2[4][64];

    const int tid = threadIdx.x;
    const int wave = tid >> 6, lane = tid & 63;
    const int q = lane >> 4, l = lane & 15;
    const int m0 = blockIdx.x * 64;

    // stage A tile (cast fp32 -> bf16)
    for (int i = tid; i < 64 * 64; i += 256) {
        int r = i >> 6;
        int c4 = (i & 63) * 4;
        int row = m0 + r;
        if (row >= N) row = N - 1;
        const float4 v = *(const float4*)(nf + (size_t)row * 256 + c4);
        bf16_t* dst = &A[r][c4];
        dst[0] = (bf16_t)v.x; dst[1] = (bf16_t)v.y; dst[2] = (bf16_t)v.z; dst[3] = (bf16_t)v.w;
    }
    __syncthreads();

    f32x4 acc[4][4];
    for (int rt = 0; rt < 4; rt++)
        for (int ct = 0; ct < 4; ct++)
            acc[rt][ct] = (f32x4){0.f, 0.f, 0.f, 0.f};

    for (int kc = 0; kc < 8; kc++) {
        bf16x8 bf[4];
        for (int ct = 0; ct < 4; ct++) {
            int n = wave * 64 + ct * 16 + l;
            bf[ct] = *(const bf16x8*)(wT + (size_t)n * 256 + kc * 32 + q * 8);
        }
        bf16x8 af[4];
        for (int rt = 0; rt < 4; rt++)
            af[rt] = *(const bf16x8*)(&A[rt * 16 + l][kc * 32 + q * 8]);
        for (int rt = 0; rt < 4; rt++)
            for (int ct = 0; ct < 4; ct++)
                acc[rt][ct] = __builtin_amdgcn_mfma_f32_16x16x32_bf16(af[rt], bf[ct], acc[rt][ct], 0, 0, 0);
    }

    // epilogue
    float bias[4], w1[4], w2[4];
    for (int ct = 0; ct < 4; ct++) {
        int n = wave * 64 + ct * 16 + l;
        bias[ct] = wb[n];
        w1[ct] = aW[n];
        w2[ct] = aW[256 + n];
    }
    for (int rt = 0; rt < 4; rt++) {
        float rs1[4] = {0.f, 0.f, 0.f, 0.f};
        float rs2[4] = {0.f, 0.f, 0.f, 0.f};
        for (int ct = 0; ct < 4; ct++) {
            int col = wave * 64 + ct * 16 + l;
            for (int r = 0; r < 4; r++) {
                float p = lrelu(acc[rt][ct][r] + bias[ct]);
                int row = m0 + rt * 16 + q * 4 + r;
                if (row < N) h[(size_t)row * 256 + col] = (bf16_t)p;
                rs1[r] += p * w1[ct];
                rs2[r] += p * w2[ct];
            }
        }
        for (int off = 1; off < 16; off <<= 1) {
            for (int r = 0; r < 4; r++) {
                rs1[r] += __shfl_xor(rs1[r], off, 64);
                rs2[r] += __shfl_xor(rs2[r], off, 64);
            }
        }
        if (l == 0) {
            for (int r = 0; r < 4; r++) {
                p1[wave][rt * 16 + q * 4 + r] = rs1[r];
                p2[wave][rt * 16 + q * 4 + r] = rs2[r];
            }
        }
    }
    __syncthreads();
    if (tid < 64 && m0 + tid < N) {
        s1[m0 + tid] = p1[0][tid] + p1[1][tid] + p1[2][tid] + p1[3][tid];
        s2[m0 + tid] = p2[0][tid] + p2[1][tid] + p2[2][tid] + p2[3][tid];
    }
}

// ---------------------------------------------------------------------------
// Edge projection: s3[e] = lrelu(ef[e] @ ewW + ewb) . aW[512:768] + a_b
// edge_h never materialized. Tile: 64 edges/block, 256 threads (4 waves).
// ---------------------------------------------------------------------------
__global__ __launch_bounds__(256) void edge_proj(const float* __restrict__ ef,
                                                 const bf16_t* __restrict__ ewT,
                                                 const float* __restrict__ eb,
                                                 const float* __restrict__ aW,
                                                 const float* __restrict__ ab,
                                                 float* __restrict__ s3, int E) {
    __shared__ bf16_t A[64][136];  // 128 + 8 pad (stride 272B = 17*16B)
    __shared__ float part[4][64];

    const int tid = threadIdx.x;
    const int wave = tid >> 6, lane = tid & 63;
    const int q = lane >> 4, l = lane & 15;
    const int m0 = blockIdx.x * 64;

    // B fragments resident in registers: [ct][kc]
    bf16x8 bfrag[4][4];
    for (int ct = 0; ct < 4; ct++) {
        int n = wave * 64 + ct * 16 + l;
        for (int kc = 0; kc < 4; kc++)
            bfrag[ct][kc] = *(const bf16x8*)(ewT + (size_t)n * 128 + kc * 32 + q * 8);
    }

    // stage A tile
    for (int i = tid; i < 64 * 32; i += 256) {
        int r = i >> 5;
        int c4 = (i & 31) * 4;
        int row = m0 + r;
        if (row >= E) row = E - 1;
        const float4 v = *(const float4*)(ef + (size_t)row * 128 + c4);
        bf16_t* dst = &A[r][c4];
        dst[0] = (bf16_t)v.x; dst[1] = (bf16_t)v.y; dst[2] = (bf16_t)v.z; dst[3] = (bf16_t)v.w;
    }
    __syncthreads();

    f32x4 acc[4][4];
    for (int rt = 0; rt < 4; rt++)
        for (int ct = 0; ct < 4; ct++)
            acc[rt][ct] = (f32x4){0.f, 0.f, 0.f, 0.f};

    for (int kc = 0; kc < 4; kc++) {
        bf16x8 af[4];
        for (int rt = 0; rt < 4; rt++)
            af[rt] = *(const bf16x8*)(&A[rt * 16 + l][kc * 32 + q * 8]);
        for (int rt = 0; rt < 4; rt++)
            for (int ct = 0; ct < 4; ct++)
                acc[rt][ct] = __builtin_amdgcn_mfma_f32_16x16x32_bf16(af[rt], bfrag[ct][kc], acc[rt][ct], 0, 0, 0);
    }

    // epilogue: lrelu(P + eb) * aW3, reduce over cols
    float bias[4], w3[4];
    for (int ct = 0; ct < 4; ct++) {
        int n = wave * 64 + ct * 16 + l;
        bias[ct] = eb[n];
        w3[ct] = aW[512 + n];
    }
    for (int rt = 0; rt < 4; rt++) {
        float rs[4] = {0.f, 0.f, 0.f, 0.f};
        for (int ct = 0; ct < 4; ct++) {
            for (int r = 0; r < 4; r++) {
                float p = lrelu(acc[rt][ct][r] + bias[ct]);
                rs[r] += p * w3[ct];
            }
        }
        for (int off = 1; off < 16; off <<= 1)
            for (int r = 0; r < 4; r++) rs[r] += __shfl_xor(rs[r], off, 64);
        if (l == 0)
            for (int r = 0; r < 4; r++) part[wave][rt * 16 + q * 4 + r] = rs[r];
    }
    __syncthreads();
    if (tid < 64 && m0 + tid < E) {
        s3[m0 + tid] = part[0][tid] + part[1][tid] + part[2][tid] + part[3][tid] + ab[0];
    }
}

// ---------------------------------------------------------------------------
// CSR build
// ---------------------------------------------------------------------------
__global__ void count_edges(const int* __restrict__ tgt, int* __restrict__ counts, int E) {
    int e = blockIdx.x * blockDim.x + threadIdx.x;
    if (e < E) atomicAdd(&counts[tgt[e]], 1);
}

__global__ __launch_bounds__(256) void scan_kernel(const int* __restrict__ counts,
                                                   int* __restrict__ rowstart, int N) {
    __shared__ int sdata[256];
    int t = threadIdx.x;
    int CH = (N + 255) >> 8;
    int i0 = t * CH;
    int sum = 0;
    for (int i = 0; i < CH; i++) {
        int idx = i0 + i;
        if (idx < N) sum += counts[idx];
    }
    sdata[t] = sum;
    __syncthreads();
    for (int off = 1; off < 256; off <<= 1) {
        int v = (t >= off) ? sdata[t - off] : 0;
        __syncthreads();
        sdata[t] += v;
        __syncthreads();
    }
    int run = sdata[t] - sum;  // exclusive prefix
    for (int i = 0; i < CH; i++) {
        int idx = i0 + i;
        if (idx < N) {
            rowstart[idx] = run;
            run += counts[idx];
        }
    }
    if (t == 255) rowstart[N] = sdata[255];
}

__global__ void fill_edges(const int* __restrict__ tgt, const int* __restrict__ rowstart,
                           int* __restrict__ cursor, int* __restrict__ elist, int E) {
    int e = blockIdx.x * blockDim.x + threadIdx.x;
    if (e < E) {
        int t = tgt[e];
        int p = atomicAdd(&cursor[t], 1);
        elist[rowstart[t] + p] = e;
    }
}

// ---------------------------------------------------------------------------
// Per-node: logits -> segment softmax -> weighted neighbor sum -> lrelu
// One block (256 threads) per node.
// ---------------------------------------------------------------------------
#define MAXDEG 2048
__global__ __launch_bounds__(256) void aggregate(const int* __restrict__ nbr,
                                                 const int* __restrict__ rowstart,
                                                 const int* __restrict__ elist,
                                                 const float* __restrict__ s1,
                                                 const float* __restrict__ s2,
                                                 const float* __restrict__ s3,
                                                 const bf16_t* __restrict__ h,
                                                 float* __restrict__ out) {
    __shared__ float ealpha[MAXDEG];
    __shared__ int enbr[MAXDEG];
    __shared__ float red[8];

    const int n = blockIdx.x;
    const int tid = threadIdx.x;
    const int rs = rowstart[n];
    int deg = rowstart[n + 1] - rs;
    if (deg > MAXDEG) deg = MAXDEG;

    const float sv1 = s1[n];
    for (int i = tid; i < deg; i += 256) {
        int e = elist[rs + i];
        int j = nbr[e];
        enbr[i] = j;
        ealpha[i] = sv1 + s2[j] + s3[e];
    }
    __syncthreads();

    // block max
    float m = -1e30f;
    for (int i = tid; i < deg; i += 256) m = fmaxf(m, ealpha[i]);
    for (int off = 32; off > 0; off >>= 1) m = fmaxf(m, __shfl_xor(m, off, 64));
    if ((tid & 63) == 0) red[tid >> 6] = m;
    __syncthreads();
    m = fmaxf(fmaxf(red[0], red[1]), fmaxf(red[2], red[3]));

    // exp + block sum
    float ssum = 0.f;
    for (int i = tid; i < deg; i += 256) {
        float ex = expf(ealpha[i] - m);
        ealpha[i] = ex;
        ssum += ex;
    }
    for (int off = 32; off > 0; off >>= 1) ssum += __shfl_xor(ssum, off, 64);
    if ((tid & 63) == 0) red[4 + (tid >> 6)] = ssum;
    __syncthreads();
    float S = red[4] + red[5] + red[6] + red[7];
    float inv = (deg > 0 && S > 0.f) ? 1.0f / S : 0.f;

    // weighted sum over neighbors: thread tid = feature dim
    float acc = 0.f;
    for (int i = 0; i < deg; i++) {
        acc += ealpha[i] * (float)h[(size_t)enbr[i] * 256 + tid];
    }
    out[(size_t)n * 256 + tid] = lrelu(acc * inv);
}

// ---------------------------------------------------------------------------
extern "C" void kernel_launch(void* const* d_in, const int* in_sizes, int n_in,
                              void* d_out, int out_size, void* d_ws, size_t ws_size,
                              hipStream_t stream) {
    const float* nf  = (const float*)d_in[0];
    const float* ef  = (const float*)d_in[1];
    const int*  eidx = (const int*)d_in[2];
    const float* wW  = (const float*)d_in[3];
    const float* wb  = (const float*)d_in[4];
    const float* ewW = (const float*)d_in[5];
    const float* ewb = (const float*)d_in[6];
    const float* aW  = (const float*)d_in[7];
    const float* ab  = (const float*)d_in[8];
    float* out = (float*)d_out;

    const int N = in_sizes[0] / DH;   // 10000
    const int E = in_sizes[1] / DE;   // 320000
    const int* tgt = eidx;
    const int* nbr = eidx + E;

    char* ws = (char*)d_ws;
    size_t off = 0;
    auto alloc = [&](size_t bytes) -> void* {
        void* p = ws + off;
        off += (bytes + 255) & ~(size_t)255;
        return p;
    };
    bf16_t* wT      = (bf16_t*)alloc((size_t)256 * 256 * 2);
    bf16_t* ewT     = (bf16_t*)alloc((size_t)256 * 128 * 2);
    bf16_t* h       = (bf16_t*)alloc((size_t)N * 256 * 2);
    float*  s1      = (float*)alloc((size_t)N * 4);
    float*  s2      = (float*)alloc((size_t)N * 4);
    float*  s3      = (float*)alloc((size_t)E * 4);
    int*    counts  = (int*)alloc((size_t)N * 4);
    int*    cursor  = (int*)alloc((size_t)N * 4);
    int*    rowstart= (int*)alloc((size_t)(N + 1) * 4);
    int*    elist   = (int*)alloc((size_t)E * 4);

    prep_weights<<<256, 256, 0, stream>>>(wW, ewW, wT, ewT);
    node_proj<<<(N + 63) / 64, 256, 0, stream>>>(nf, wT, wb, aW, h, s1, s2, N);
    edge_proj<<<(E + 63) / 64, 256, 0, stream>>>(ef, ewT, ewb, aW, ab, s3, E);

    size_t zspan = (size_t)((char*)cursor + (size_t)N * 4 - (char*)counts);
    hipMemsetAsync(counts, 0, zspan, stream);
    count_edges<<<(E + 255) / 256, 256, 0, stream>>>(tgt, counts, E);
    scan_kernel<<<1, 256, 0, stream>>>(counts, rowstart, N);
    fill_edges<<<(E + 255) / 256, 256, 0, stream>>>(tgt, rowstart, cursor, elist, E);
    aggregate<<<N, 256, 0, stream>>>(nbr, rowstart, elist, s1, s2, s3, h, out);
}